// Round 1
// 550.664 us; speedup vs baseline: 1.0747x; 1.0747x over previous
//
#include <hip/hip_runtime.h>
#include <hip/hip_bf16.h>

// B=32, S=2048, H=1024, U=1024. M = B*S = 65536 rows.
// score[b,s] = sum_u tanh(enc[b,s,:]@W1[:,u] + W1b[u] + ph[b,u]) * Vw[u]  (+Vb cancels in softmax)
// out = softmax_s(score)

typedef __bf16 bf16x8 __attribute__((ext_vector_type(8)));
typedef float  f32x4  __attribute__((ext_vector_type(4)));

#define HDIM 1024
#define UDIM 1024
#define SDIM 2048
#define MROWS 65536
#define NT 16          // K tiles of 64 for the 8-phase kernel

__device__ inline unsigned short f2bf(float x) {
    return __builtin_bit_cast(unsigned short, (__bf16)x);
}

// fast tanh: tanh(x) = sign(x) * (1-e^{-2|x|})/(1+e^{-2|x|}). z in (0,1].
__device__ inline float fast_tanh(float x) {
    float z = __expf(-2.0f * __builtin_fabsf(x));
    float t = __fdividef(1.0f - z, 1.0f + z);
    return __builtin_copysignf(t, x);
}

// async 16B global->LDS (m97: width=16 emits global_load_lds_dwordx4)
#define GLDS16(gp, lp)                                                              \
    __builtin_amdgcn_global_load_lds(                                               \
        (const __attribute__((address_space(1))) unsigned int*)(gp),                \
        (__attribute__((address_space(3))) unsigned int*)(lp), 16, 0, 0)

// ---------------- prep: enc fp32 -> bf16 (pure BW pass) ----------------
__global__ __launch_bounds__(256) void cvt_kernel(const float* __restrict__ in,
                                                  unsigned short* __restrict__ out) {
    size_t i = ((size_t)blockIdx.x * 256 + threadIdx.x) * 8;
    const float4 f0 = *(const float4*)(in + i);
    const float4 f1 = *(const float4*)(in + i + 4);
    ushort4 h0, h1;
    h0.x = f2bf(f0.x); h0.y = f2bf(f0.y); h0.z = f2bf(f0.z); h0.w = f2bf(f0.w);
    h1.x = f2bf(f1.x); h1.y = f2bf(f1.y); h1.z = f2bf(f1.z); h1.w = f2bf(f1.w);
    *(ushort4*)(out + i) = h0;
    *(ushort4*)(out + i + 4) = h1;
}

// ---------------- prep: W1 [H,U] fp32 -> W1T [U,H] bf16 ----------------
__global__ void w1t_kernel(const float* __restrict__ W1, unsigned short* __restrict__ W1T) {
    __shared__ float tile[32][33];
    int bx = blockIdx.x;   // u tile
    int by = blockIdx.y;   // h tile
    int tx = threadIdx.x, ty = threadIdx.y;   // (32,8)
#pragma unroll
    for (int r = 0; r < 4; ++r) {
        int h = by * 32 + ty + r * 8;
        int u = bx * 32 + tx;
        tile[ty + r * 8][tx] = W1[h * UDIM + u];
    }
    __syncthreads();
#pragma unroll
    for (int r = 0; r < 4; ++r) {
        int u = bx * 32 + ty + r * 8;
        int h = by * 32 + tx;
        W1T[u * HDIM + h] = f2bf(tile[tx][ty + r * 8]);
    }
}

// ---------------- prep: ph partials (split-K over h) ----------------
__global__ void php_kernel(const float* __restrict__ hn, const float* __restrict__ W2,
                           float* __restrict__ php) {
    int u = (blockIdx.x & 3) * 256 + threadIdx.x;
    int b = blockIdx.y;
    int hc = blockIdx.z;           // 8 chunks of 128
    int h0 = hc * 128;
    float acc = 0.f;
#pragma unroll 8
    for (int h = h0; h < h0 + 128; ++h)
        acc = fmaf(hn[b * HDIM + h], W2[h * UDIM + u], acc);
    php[(hc * 32 + b) * UDIM + u] = acc;
}

__global__ void ph_combine(const float* __restrict__ php, const float* __restrict__ W1b,
                           const float* __restrict__ W2b, float* __restrict__ ph) {
    int idx = blockIdx.x * 256 + threadIdx.x;   // 32768
    int u = idx & (UDIM - 1);
    int b = idx >> 10;
    float acc = W1b[u] + W2b[u];
#pragma unroll
    for (int p = 0; p < 8; ++p) acc += php[(p * 32 + b) * UDIM + u];
    ph[idx] = acc;
}

// =======================================================================
// 8-phase 256x256 fused GEMM (m201-style template, plain HIP).
//
// Geometry: BM=BN=256, BK=64, 512 threads = 8 waves (2M x 4N), per-wave
// output 128x64 = acc[8][4] f32x4. Grid = 256 m-tiles x 4 n-tiles = 1024.
//
// LDS: 8 half-tile slots x 16 KB (128x64 bf16 each) = 128 KiB ring.
//   tile tau occupies slots (par=tau&1): B0=4par+0, A0=+1, A1=+2, B1=+3.
//   A0 = rows 0-127, A1 = rows 128-255 of the m-tile; B0/B1 same for u-cols.
//
// Swizzle (T2): within a 128B row of 8x16B chunks, logical chunk q of row r
//   is stored at phys chunk q ^ (r&7). Staging keeps the LDS dest LINEAR
//   (global_load_lds writes base+lane*16) and pre-swizzles the per-lane
//   GLOBAL source; ds_read applies the same XOR. 64 lanes of a frag read
//   spread 8 lanes per 16B bank-group = conflict-free.
//
// Schedule (T3/T4): 4 phases per K-tile, each {ds_read frags; stage ONE
//   half-tile (2 GLDS/thread); s_barrier; 16 MFMA (setprio, T5); s_barrier}.
//   Stage targets: p0:A1(tau+1), p1:B1(tau+1), p2:B0(tau+2), p3:A0(tau+2).
//   Every overwrite of a slot is issued >=1 closing-barrier after its last
//   read (B slots last read p1, overwritten p2/p1+4; A slots last read p2,
//   overwritten p3/p0+4). Boundary wait once per tile: vmcnt(4) (the 4
//   newest loads = p2+p3 stages of the next-next tile stay in flight);
//   vmcnt(0) only before the last tile. Prologue: 6 half-tiles, vmcnt(4).
// =======================================================================
__global__ __launch_bounds__(512, 2) void score_kernel2(
    const unsigned short* __restrict__ encb, const unsigned short* __restrict__ W1T,
    const float* __restrict__ ph, const float* __restrict__ Vw,
    float* __restrict__ part) {
    __shared__ __align__(16) unsigned short smem[65536];   // 128 KiB = 8 x 16 KB slots

    const int bx = blockIdx.x;
    // XCD swizzle (T1): 1024 blocks, 8 XCDs, 128 tiles/XCD, n fastest.
    const int x = bx & 7;
    const int k = bx >> 3;
    const int tile_n = k & 3;
    const int tile_m = (x << 5) | (k >> 2);     // 0..255
    const int row0 = tile_m * 256;
    const int col0 = tile_n * 256;

    const int t = threadIdx.x;
    const int lane = t & 63;
    const int wid = t >> 6;          // 0..7
    const int wm = wid >> 2;         // 0..1  (M half)
    const int wn = wid & 3;          // 0..3  (N quarter)

    // ---- ds_read per-thread constants ----
    const int e = lane & 7;
    const int c = lane >> 4;                                        // k-chunk 0..3
    const int swz16 = (((c ^ (e & 3)) | ((e >> 2) << 2)) << 4);     // phys chunk byte (ks=0)
    const int offk0 = ((lane & 15) << 7) + swz16;                   // row*128 + swz chunk
    const int bhalf_off = (wn & 1) * 8192;                          // col quarter within B half

    // ---- staging per-thread constants (pre-swizzled global source) ----
    const int rp0 = (wid << 3) + (lane >> 3);                       // phys row 0..63
    const int gsw = ((lane & 7) ^ (rp0 & 7)) << 3;                  // logical chunk elems
    const size_t gof0 = (size_t)rp0 * HDIM + gsw;
    const size_t gof1 = gof0 + (size_t)64 * HDIM;
    const unsigned lof0 = (unsigned)(wid << 10);
    const unsigned lof1 = lof0 + 8192u;

    const unsigned short* gA0 = encb + (size_t)row0 * HDIM;
    const unsigned short* gA1 = encb + (size_t)(row0 + 128) * HDIM;
    const unsigned short* gB0 = W1T + (size_t)col0 * HDIM;
    const unsigned short* gB1 = W1T + (size_t)(col0 + 128) * HDIM;

#define STAGE(gbase, kt, slotbyte)                                          \
    do {                                                                    \
        GLDS16((gbase) + (kt) + gof0, (char*)smem + (slotbyte) + lof0);     \
        GLDS16((gbase) + (kt) + gof1, (char*)smem + (slotbyte) + lof1);     \
    } while (0)

#define LOADA(half)                                                                          \
    _Pragma("unroll") for (int fi = 0; fi < 4; ++fi)                                         \
    _Pragma("unroll") for (int ks = 0; ks < 2; ++ks)                                         \
        aF[fi][ks] = *(const bf16x8*)((const char*)smem + slotA + ((half) + fi) * 2048 +     \
                                      (offk0 ^ (ks << 6)));

#define LOADB(dst, jhalf)                                                                    \
    _Pragma("unroll") for (int fj = 0; fj < 2; ++fj)                                         \
    _Pragma("unroll") for (int ks = 0; ks < 2; ++ks)                                         \
        dst[fj][ks] = *(const bf16x8*)((const char*)smem + slotB + bhalf_off +               \
                                       ((jhalf) + fj) * 2048 + (offk0 ^ (ks << 6)));

#define MFMA8(iBase, jBase, AF, BF)                                                          \
    _Pragma("unroll") for (int fi = 0; fi < 4; ++fi)                                         \
    _Pragma("unroll") for (int fj = 0; fj < 2; ++fj)                                         \
    _Pragma("unroll") for (int ks = 0; ks < 2; ++ks)                                         \
        acc[(iBase) + fi][(jBase) + fj] = __builtin_amdgcn_mfma_f32_16x16x32_bf16(           \
            AF[fi][ks], BF[fj][ks], acc[(iBase) + fi][(jBase) + fj], 0, 0, 0);

#define SBAR __builtin_amdgcn_s_barrier()

    f32x4 acc[8][4];
#pragma unroll
    for (int i = 0; i < 8; ++i)
#pragma unroll
        for (int j = 0; j < 4; ++j)
            acc[i][j] = (f32x4){0.f, 0.f, 0.f, 0.f};

    // prologue: tile0 (B0,A0,A1,B1) + tile1 (B0,A0); oldest 8 loads = tile0.
    STAGE(gB0, 0, 0u);
    STAGE(gA0, 0, 16384u);
    STAGE(gA1, 0, 32768u);
    STAGE(gB1, 0, 49152u);
    STAGE(gB0, 64, 65536u);
    STAGE(gA0, 64, 81920u);
    asm volatile("s_waitcnt vmcnt(4)" ::: "memory");
    SBAR;

#pragma unroll 2
    for (int tau = 0; tau < NT; ++tau) {
        const unsigned sbase = (tau & 1) ? 65536u : 0u;
        const unsigned obase = 65536u - sbase;
        const unsigned slotA = sbase + (unsigned)(1 + wm) * 16384u;
        const unsigned slotB = sbase + ((wn & 2) ? 49152u : 0u);
        const int ktn1 = (tau + 1) * 64;
        const int ktn2 = (tau + 2) * 64;

        bf16x8 aF[4][2], bJ0[2][2], bJ1[2][2];

        // ---- phase 0: read A i0-3 + B j0-1; stage A1(tau+1); mfma q(0-3,0-1)
        LOADA(0);
        LOADB(bJ0, 0);
        if (tau + 1 < NT) STAGE(gA1, ktn1, obase + 32768u);
        SBAR;
        __builtin_amdgcn_s_setprio(1);
        MFMA8(0, 0, aF, bJ0);
        __builtin_amdgcn_s_setprio(0);
        SBAR;

        // ---- phase 1: read B j2-3; stage B1(tau+1); mfma q(0-3,2-3)
        LOADB(bJ1, 2);
        if (tau + 1 < NT) STAGE(gB1, ktn1, obase + 49152u);
        SBAR;
        __builtin_amdgcn_s_setprio(1);
        MFMA8(0, 2, aF, bJ1);
        __builtin_amdgcn_s_setprio(0);
        SBAR;

        // ---- phase 2: read A i4-7; stage B0(tau+2); mfma q(4-7,2-3)
        LOADA(4);
        if (tau + 2 < NT) STAGE(gB0, ktn2, sbase + 0u);
        SBAR;
        __builtin_amdgcn_s_setprio(1);
        MFMA8(4, 2, aF, bJ1);
        __builtin_amdgcn_s_setprio(0);
        SBAR;

        // ---- phase 3: stage A0(tau+2); mfma q(4-7,0-1); tile-boundary wait
        if (tau + 2 < NT) STAGE(gA0, ktn2, sbase + 16384u);
        SBAR;
        __builtin_amdgcn_s_setprio(1);
        MFMA8(4, 0, aF, bJ0);
        __builtin_amdgcn_s_setprio(0);
        if (tau < NT - 1) {
            if (tau == NT - 2) { asm volatile("s_waitcnt vmcnt(0)" ::: "memory"); }
            else               { asm volatile("s_waitcnt vmcnt(4)" ::: "memory"); }
            SBAR;
        }
    }

    // ---- epilogue: +ph -> tanh -> *Vw -> 16-lane reduce -> cross-wave LDS reduce
    __syncthreads();
    const int bidx = row0 >> 11;        // batch (2048 rows per b; 256 | 2048)
    const int colg = lane & 15;         // C/D: col = lane&15
    const int rowq = (lane >> 4) << 2;  // C/D: row = quad*4 + reg
    float vw[4], phv[4];
#pragma unroll
    for (int j = 0; j < 4; ++j) {
        int u = col0 + wn * 64 + j * 16 + colg;
        vw[j] = Vw[u];
        phv[j] = ph[bidx * UDIM + u];
    }
    float* red = (float*)smem;          // [8 waves][128 rows]
#pragma unroll
    for (int i = 0; i < 8; ++i) {
#pragma unroll
        for (int r = 0; r < 4; ++r) {
            float s = 0.f;
#pragma unroll
            for (int j = 0; j < 4; ++j) {
                float pe = acc[i][j][r] + phv[j];
                s += fast_tanh(pe) * vw[j];
            }
            s += __shfl_xor(s, 1);
            s += __shfl_xor(s, 2);
            s += __shfl_xor(s, 4);
            s += __shfl_xor(s, 8);
            if (colg == 0) red[wid * 128 + i * 16 + rowq + r] = s;
        }
    }
    __syncthreads();
    if (t < 256) {
        int wmr = t >> 7;
        int rl = t & 127;
        float s = red[(wmr * 4 + 0) * 128 + rl] + red[(wmr * 4 + 1) * 128 + rl] +
                  red[(wmr * 4 + 2) * 128 + rl] + red[(wmr * 4 + 3) * 128 + rl];
        part[(size_t)tile_n * MROWS + row0 + t] = s;
    }
#undef STAGE
#undef LOADA
#undef LOADB
#undef MFMA8
#undef SBAR
}

// ---------------- fallback GEMM (fp32 in-register convert, 16 slices) ----------------
#define BM 128
#define BN 128
#define BK 32
#define LDK 40
__global__ __launch_bounds__(256) void score_kernel_f32(
    const float* __restrict__ enc, const unsigned short* __restrict__ W1T,
    const float* __restrict__ ph, const float* __restrict__ Vw,
    float* __restrict__ part) {
    __shared__ unsigned short As[BM * LDK];
    __shared__ unsigned short Bs[BN * LDK];

    const int bx = blockIdx.x;
    const int tile_n = bx & 7;
    const int tile_m = bx >> 3;
    const int t = threadIdx.x;
    const int lane = t & 63;
    const int wid = t >> 6;
    const int wm = wid >> 1, wn = wid & 1;

    const int row0 = tile_m * BM;
    const int col0 = tile_n * BN;

    f32x4 acc[4][4];
#pragma unroll
    for (int i = 0; i < 4; ++i)
#pragma unroll
        for (int j = 0; j < 4; ++j)
            acc[i][j] = (f32x4){0.f, 0.f, 0.f, 0.f};

    const int mrow = lane & 15;
    const int kq = (lane >> 4) * 8;

    for (int kt = 0; kt < HDIM; kt += BK) {
        __syncthreads();
#pragma unroll
        for (int i = 0; i < 4; ++i) {
            int cc = t + 256 * i;
            int r = cc >> 3;
            int kc = (cc & 7) * 4;
            const float4 f = *(const float4*)(enc + (size_t)(row0 + r) * HDIM + kt + kc);
            ushort4 h;
            h.x = f2bf(f.x); h.y = f2bf(f.y); h.z = f2bf(f.z); h.w = f2bf(f.w);
            *(ushort4*)(As + r * LDK + kc) = h;
        }
#pragma unroll
        for (int i = 0; i < 2; ++i) {
            int cc = t + 256 * i;
            int r = cc >> 2;
            int kc = (cc & 3) * 8;
            const uint4 v = *(const uint4*)(W1T + (size_t)(col0 + r) * HDIM + kt + kc);
            *(uint4*)(Bs + r * LDK + kc) = v;
        }
        __syncthreads();

        bf16x8 a[4], bb[4];
#pragma unroll
        for (int i = 0; i < 4; ++i)
            a[i] = *reinterpret_cast<const bf16x8*>(As + (wm * 64 + i * 16 + mrow) * LDK + kq);
#pragma unroll
        for (int j = 0; j < 4; ++j)
            bb[j] = *reinterpret_cast<const bf16x8*>(Bs + (wn * 64 + j * 16 + mrow) * LDK + kq);
#pragma unroll
        for (int i = 0; i < 4; ++i)
#pragma unroll
            for (int j = 0; j < 4; ++j)
                acc[i][j] = __builtin_amdgcn_mfma_f32_16x16x32_bf16(a[i], bb[j], acc[i][j], 0, 0, 0);
    }

    const int b = row0 >> 11;
    const int colg = lane & 15;
    const int rowq = (lane >> 4) * 4;
    float vw[4], phv[4];
#pragma unroll
    for (int j = 0; j < 4; ++j) {
        int u = col0 + wn * 64 + j * 16 + colg;
        vw[j] = Vw[u];
        phv[j] = ph[b * UDIM + u];
    }
#pragma unroll
    for (int i = 0; i < 4; ++i) {
#pragma unroll
        for (int r = 0; r < 4; ++r) {
            float s = 0.f;
#pragma unroll
            for (int j = 0; j < 4; ++j) {
                float pe = acc[i][j][r] + phv[j];
                s += fast_tanh(pe) * vw[j];
            }
            s += __shfl_xor(s, 1);
            s += __shfl_xor(s, 2);
            s += __shfl_xor(s, 4);
            s += __shfl_xor(s, 8);
            if (colg == 0) {
                int row = row0 + wm * 64 + i * 16 + rowq + r;
                part[(size_t)(tile_n * 2 + wn) * MROWS + row] = s;
            }
        }
    }
}

// ---------------- final: sum partial slices + softmax over s ----------------
__global__ void softmax4_kernel(const float* __restrict__ part, float* __restrict__ out) {
    int b = blockIdx.x;
    int t = threadIdx.x;   // 256
    __shared__ float sred[4];
    float v[8];
    float lmax = -3.4e38f;
#pragma unroll
    for (int i = 0; i < 8; ++i) {
        int s = t + i * 256;
        float sum = 0.f;
#pragma unroll
        for (int p = 0; p < 4; ++p) sum += part[(size_t)p * MROWS + b * SDIM + s];
        v[i] = sum;
        lmax = fmaxf(lmax, sum);
    }
#pragma unroll
    for (int off = 1; off < 64; off <<= 1) lmax = fmaxf(lmax, __shfl_xor(lmax, off));
    if ((t & 63) == 0) sred[t >> 6] = lmax;
    __syncthreads();
    float bmax = fmaxf(fmaxf(sred[0], sred[1]), fmaxf(sred[2], sred[3]));
    __syncthreads();
    float lsum = 0.f;
#pragma unroll
    for (int i = 0; i < 8; ++i) {
        v[i] = expf(v[i] - bmax);
        lsum += v[i];
    }
#pragma unroll
    for (int off = 1; off < 64; off <<= 1) lsum += __shfl_xor(lsum, off);
    if ((t & 63) == 0) sred[t >> 6] = lsum;
    __syncthreads();
    float inv = 1.0f / (sred[0] + sred[1] + sred[2] + sred[3]);
#pragma unroll
    for (int i = 0; i < 8; ++i) out[b * SDIM + t + i * 256] = v[i] * inv;
}

__global__ void softmax16_kernel(const float* __restrict__ part, float* __restrict__ out) {
    int b = blockIdx.x;
    int t = threadIdx.x;   // 256
    __shared__ float sred[4];
    float v[8];
    float lmax = -3.4e38f;
#pragma unroll
    for (int i = 0; i < 8; ++i) {
        int s = t + i * 256;
        float sum = 0.f;
#pragma unroll
        for (int p = 0; p < 16; ++p) sum += part[(size_t)p * MROWS + b * SDIM + s];
        v[i] = sum;
        lmax = fmaxf(lmax, sum);
    }
#pragma unroll
    for (int off = 1; off < 64; off <<= 1) lmax = fmaxf(lmax, __shfl_xor(lmax, off));
    if ((t & 63) == 0) sred[t >> 6] = lmax;
    __syncthreads();
    float bmax = fmaxf(fmaxf(sred[0], sred[1]), fmaxf(sred[2], sred[3]));
    __syncthreads();
    float lsum = 0.f;
#pragma unroll
    for (int i = 0; i < 8; ++i) {
        v[i] = expf(v[i] - bmax);
        lsum += v[i];
    }
#pragma unroll
    for (int off = 1; off < 64; off <<= 1) lsum += __shfl_xor(lsum, off);
    if ((t & 63) == 0) sred[t >> 6] = lsum;
    __syncthreads();
    float inv = 1.0f / (sred[0] + sred[1] + sred[2] + sred[3]);
#pragma unroll
    for (int i = 0; i < 8; ++i) out[b * SDIM + t + i * 256] = v[i] * inv;
}

extern "C" void kernel_launch(void* const* d_in, const int* in_sizes, int n_in,
                              void* d_out, int out_size, void* d_ws, size_t ws_size,
                              hipStream_t stream) {
    const float* enc = (const float*)d_in[0];
    const float* hn  = (const float*)d_in[1];
    const float* W1  = (const float*)d_in[2];
    const float* W1b = (const float*)d_in[3];
    const float* W2  = (const float*)d_in[4];
    const float* W2b = (const float*)d_in[5];
    const float* Vw  = (const float*)d_in[6];
    // d_in[7] = V_b: softmax is shift-invariant per batch -> exactly cancels.
    float* out = (float*)d_out;

    char* ws = (char*)d_ws;
    const size_t ENCB_BYTES = (size_t)MROWS * HDIM * 2;        // 128 MB
    const size_t NEED = ENCB_BYTES + (2u << 20) + (128u << 10) + (1u << 20) + (4u << 20);

    if (ws_size >= NEED) {
        unsigned short* encb = (unsigned short*)ws;                                  // 128 MB
        unsigned short* W1T  = (unsigned short*)(ws + ENCB_BYTES);                   // 2 MB
        float* ph   = (float*)(ws + ENCB_BYTES + (2u << 20));                        // 128 KB
        float* php  = (float*)(ws + ENCB_BYTES + (2u << 20) + (128u << 10));         // 1 MB
        float* part = (float*)(ws + ENCB_BYTES + (2u << 20) + (128u << 10) + (1u << 20)); // 4 MB

        cvt_kernel<<<32768, 256, 0, stream>>>(enc, encb);
        w1t_kernel<<<dim3(32, 32), dim3(32, 8), 0, stream>>>(W1, W1T);
        php_kernel<<<dim3(4, 32, 8), 256, 0, stream>>>(hn, W2, php);
        ph_combine<<<128, 256, 0, stream>>>(php, W1b, W2b, ph);
        score_kernel2<<<dim3(1024), 512, 0, stream>>>(encb, W1T, ph, Vw, part);
        softmax4_kernel<<<32, 256, 0, stream>>>(part, out);
    } else {
        unsigned short* W1T = (unsigned short*)ws;
        float* ph   = (float*)(ws + (2u << 20));
        float* php  = (float*)(ws + (2u << 20) + (128u << 10));
        float* part = (float*)(ws + (2u << 20) + (128u << 10) + (1u << 20));

        w1t_kernel<<<dim3(32, 32), dim3(32, 8), 0, stream>>>(W1, W1T);
        php_kernel<<<dim3(4, 32, 8), 256, 0, stream>>>(hn, W2, php);
        ph_combine<<<128, 256, 0, stream>>>(php, W1b, W2b, ph);
        score_kernel_f32<<<dim3(4096), 256, 0, stream>>>(enc, W1T, ph, Vw, part);
        softmax16_kernel<<<32, 256, 0, stream>>>(part, out);
    }
}